// Round 5
// baseline (161.621 us; speedup 1.0000x reference)
//
#include <hip/hip_runtime.h>
#include <math.h>

#define SC 4
#define BB 2
#define CC 32
#define HH 256
#define WW 512
#define CH (HH / SC)   // 64
#define CW (WW / SC)   // 128

using f16x8 = __attribute__((ext_vector_type(8))) _Float16;
using f32x4 = __attribute__((ext_vector_type(4))) float;
using f32x2 = __attribute__((ext_vector_type(2))) float;

// Direction metadata (output channel order: c, l, r, t, b, lt, rt, lb, rb)
//   s0: 0 -> xv (x[w%4]), 1 -> 4-(w%4) (D1), 2 -> (w%4)+1 (D2)
//   s1: 0 -> yv (x[h%4]), 1 -> 4-(h%4) (D3), 2 -> (h%4)+1 (D4)
// constexpr: the d-loop is fully unrolled, these fold to immediates.
constexpr int K_dh[9] = {0, 0, 0, -1, 1, -1, -1, 1, 1};
constexpr int K_dw[9] = {0, -1, 1, 0, 0, -1, 1, -1, 1};
constexpr int K_s0[9] = {0, 1, 2, 0, 0, 1, 2, 0, 0};
constexpr int K_s1[9] = {0, 0, 0, 1, 2, 0, 0, 1, 2};

template <int CTRL>
__device__ __forceinline__ float dpp_add(float v) {
    union { float f; int i; } u, r;
    u.f = v;
    r.i = __builtin_amdgcn_update_dpp(0, u.i, CTRL, 0xF, 0xF, true);
    return v + r.f;
}

// 8-lane butterfly sum on the VALU pipe (no LDS). Lanes m16 8..15 carry exact
// zeros (w3v/w2B zero-padded), so a 4th step (row_mirror) would only add 0;
// dropping it is bit-identical for lanes 0..7 (the ones that select/store).
__device__ __forceinline__ float sum8(float v) {
    v = dpp_add<0xB1>(v);    // quad_perm [1,0,3,2]  : lane ^ 1
    v = dpp_add<0x4E>(v);    // quad_perm [2,3,0,1]  : lane ^ 2
    v = dpp_add<0x141>(v);   // row_half_mirror      : pairs quads within 8
    return v;
}

// Pre-pass: ALr[(b*CH+cy)*CW+cx][o] = sum_c w0[o*66+c] * lr[b][c][cy][cx]  (fp32)
__global__ __launch_bounds__(256) void alr_prepass(const float* __restrict__ lr,
                                                   const float* __restrict__ w0,
                                                   float* __restrict__ alr) {
    const int idx = blockIdx.x * 256 + threadIdx.x;
    if (idx >= BB * CH * CW) return;
    const int b = idx / (CH * CW);
    const int cell = idx - b * (CH * CW);
    const float* lp = lr + (size_t)b * CC * CH * CW + cell;
    float lv[32];
#pragma unroll
    for (int c = 0; c < 32; c++) lv[c] = lp[(size_t)c * (CH * CW)];
    float acc[32];
#pragma unroll
    for (int o = 0; o < 32; o++) {
        float a = 0.f;
#pragma unroll
        for (int c = 0; c < 32; c++) a = fmaf(lv[c], w0[o * 66 + c], a);
        acc[o] = a;
    }
    float4* op = (float4*)(alr + (size_t)idx * 32);
#pragma unroll
    for (int j = 0; j < 8; j++)
        op[j] = make_float4(acc[4 * j], acc[4 * j + 1], acc[4 * j + 2], acc[4 * j + 3]);
}

// MFMA main. BLOCK-SLOT restructure (R4 post-mortem): every config so far
// saturates at ~2.5-3 resident BLOCKS/CU (R0 23.6% occ @3-blk LDS cap; R1
// 30.8% after LDS cap lifted to 10; R4 32.4% after grid doubled to 8-blk/CU
// worth of work) while R3 (VGPR=32, spilling) hit 70% — the residency
// limiter tracks workgroup slots, not LDS/grid. So: pack 16 waves per block
// (1024 thr), 512 blocks -> 2 blocks/CU = 32 waves/CU inside ~2 slots.
// Per-thread code is BIT-IDENTICAL to R4; only ownership mapping changed:
// block covers 16 h-rows x 32 w-px; wave ty (0..15) owns h-row by*16+ty.
// __launch_bounds__(1024,4): same 128-VGPR cap as (256,4) — R3 lesson:
// never force 8 waves/EU on the allocator (VGPR=32 + 80MB scratch spill).
// Per t (16 px tile): Phase A (hr . w0hr via 2 MFMAs) -> s_ahr -> ahr in f32
// regs once, then 9 unrolled directions:
//   A1 = leaky(ahr + alr[cell(d)] + dist(d)) -> MFMA(w1) -> s_d2 glue ->
//   MFMA(w2) -> 3-step DPP butterfly layer-4 reduce -> logit in reg.
// In-lane softmax; lanes m16<4 store 64B/direction. Fragment layouts
// unchanged (guide §3, m89/m120).
template <bool USE_WS>
__global__ __launch_bounds__(1024, 4) void ercm_mfma(const float* __restrict__ hr,
                                                     const float* __restrict__ lr,
                                                     const float* __restrict__ alr,
                                                     const float* __restrict__ w0,
                                                     const float* __restrict__ w1,
                                                     const float* __restrict__ w2,
                                                     const float* __restrict__ w3,
                                                     float* __restrict__ out) {
    __shared__ _Float16 s_alr[60 * 40];      // [cell][o], 6 x 10 halo of coarse cells
    __shared__ _Float16 s_ahr[16][16 * 40];  // per wave: [px-in-tile][o]
    __shared__ _Float16 s_d2[16][16 * 40];   // per wave: [px-in-tile][ch2], cols 16..31 zeroed once

    const int tid = threadIdx.x;
    const int lane = tid & 63;
    const int ty = tid >> 6;       // wave id = h-row within block (0..15)
    const int m16 = lane & 15;
    const int q = lane >> 4;       // quad
    const int bx = blockIdx.x;     // 0..15
    const int by = blockIdx.y;     // 0..15
    const int b = blockIdx.z;      // 0..1
    const int h = by * 16 + ty;
    const int wp0 = bx * 32;
    const size_t HW = (size_t)HH * WW;

    // ---- stage ALr halo tile (6 x 10 coarse cells), f16 ----
    // halo origin: coarse row by*4 - 1, coarse col bx*8 - 1
    if (USE_WS) {
        for (int i = tid; i < 60 * 32; i += 1024) {
            const int c = i & 31, cell = i >> 5;
            const int row = cell / 10, col = cell - row * 10;
            const int gcy = by * 4 - 1 + row, gcx = bx * 8 - 1 + col;
            float v = 0.f;
            if ((unsigned)gcy < (unsigned)CH && (unsigned)gcx < (unsigned)CW)
                v = alr[(((size_t)b * CH + gcy) * CW + gcx) * 32 + c];
            s_alr[cell * 40 + c] = (_Float16)v;
        }
    } else {
        for (int i = tid; i < 60 * 32; i += 1024) {
            const int o = i & 31, cell = i >> 5;
            const int row = cell / 10, col = cell - row * 10;
            const int gcy = by * 4 - 1 + row, gcx = bx * 8 - 1 + col;
            float a = 0.f;
            if ((unsigned)gcy < (unsigned)CH && (unsigned)gcx < (unsigned)CW) {
                const float* lp = lr + (size_t)b * CC * CH * CW + (size_t)gcy * CW + gcx;
#pragma unroll
                for (int c = 0; c < 32; c++) a = fmaf(lp[(size_t)c * (CH * CW)], w0[o * 66 + c], a);
            }
            s_alr[cell * 40 + o] = (_Float16)a;
        }
    }

    // ---- load weight B-fragments (once) ----
    f16x8 w1B, w0hB0, w0hB1, w2B;
    {
        const float* p1 = w1 + m16 * 32 + q * 8;
        const float* p00 = w0 + m16 * 66 + 32 + q * 8;
        const float* p01 = w0 + (m16 + 16) * 66 + 32 + q * 8;
        const bool w2ok = (m16 < 8) && (q < 2);
#pragma unroll
        for (int j = 0; j < 8; j++) {
            w1B[j] = (_Float16)p1[j];
            w0hB0[j] = (_Float16)p00[j];
            w0hB1[j] = (_Float16)p01[j];
            w2B[j] = (_Float16)(w2ok ? w2[m16 * 16 + q * 8 + j] : 0.f);
        }
    }
    // layer-1 distance weights for this lane's channels o=q*8+j, as f32x2 pairs
    f32x2 w0d0v[4], w0d1v[4];
#pragma unroll
    for (int jp = 0; jp < 4; jp++) {
        w0d0v[jp] = f32x2{w0[(q * 8 + 2 * jp) * 66 + 64], w0[(q * 8 + 2 * jp + 1) * 66 + 64]};
        w0d1v[jp] = f32x2{w0[(q * 8 + 2 * jp) * 66 + 65], w0[(q * 8 + 2 * jp + 1) * 66 + 65]};
    }
    const float w3v = (m16 < 8) ? w3[m16] : 0.f;

    // per-lane distance operand values (pixel phase xm = w%4; ym wave-uniform)
    const int xm = m16 & 3;
    const float xv = (float)(xm < 2 ? xm - 2 : xm - 1);
    const float x1 = (float)(4 - xm), x2 = (float)(xm + 1);
    const int ym = h & 3;
    const float yv = (float)(ym < 2 ? ym - 2 : ym - 1);
    const float y1 = (float)(4 - ym), y2 = (float)(ym + 1);

    _Float16* sa = s_ahr[ty];
    _Float16* sd = s_d2[ty];
    // zero the s_d2 pad (cols 16..31) once: layer-3 A-frag k=16..31 then reads
    // exact zeros (w2B is also zero there), so no exec-mask branch per load.
#pragma unroll
    for (int r = 0; r < 4; r++) sd[(q * 4 + r) * 40 + 16 + m16] = (_Float16)0.f;

    __syncthreads();  // s_alr staged (everything else is per-wave)

    const float* hp = hr + (size_t)b * CC * HW + (size_t)h * WW + wp0;

#pragma unroll 1
    for (int t = 0; t < 2; t++) {
        // ---- Phase A for this 16-px tile: ahr = hr . w0hr via 2 MFMAs ----
        f16x8 a;
#pragma unroll
        for (int j = 0; j < 8; j++) a[j] = (_Float16)hp[(size_t)(q * 8 + j) * HW + t * 16 + m16];
        f32x4 acc0 = {0.f, 0.f, 0.f, 0.f}, acc1 = {0.f, 0.f, 0.f, 0.f};
        acc0 = __builtin_amdgcn_mfma_f32_16x16x32_f16(a, w0hB0, acc0, 0, 0, 0);
        acc1 = __builtin_amdgcn_mfma_f32_16x16x32_f16(a, w0hB1, acc1, 0, 0, 0);
#pragma unroll
        for (int r = 0; r < 4; r++) {
            sa[(q * 4 + r) * 40 + m16] = (_Float16)acc0[r];        // D col = ch 0..15
            sa[(q * 4 + r) * 40 + 16 + m16] = (_Float16)acc1[r];   // ch 16..31
        }
        // hoist ahr to f32 registers ONCE (reused by all 9 directions)
        const f16x8 ahv = *(const f16x8*)&sa[m16 * 40 + q * 8];
        f32x2 ah2[4];
#pragma unroll
        for (int jp = 0; jp < 4; jp++)
            ah2[jp] = f32x2{(float)ahv[2 * jp], (float)ahv[2 * jp + 1]};

        // alr halo: one base address per t anchored at the (dh=-1,dw=-1)
        // corner; per-d cell becomes a compile-time ds offset immediate
        // ((1+dh)*10 + (1+dw)) * 80 bytes. Wave's own halo row = (ty>>2)+1.
        const _Float16* alp =
            &s_alr[((ty >> 2) * 10 + ((t * 16 + m16) >> 2)) * 40 + q * 8];
        const int wown = wp0 + t * 16 + q * 4 + xm;  // this lane's own pixel

        float l[9];
#pragma unroll
        for (int d = 0; d < 9; d++) {
            const int dh = K_dh[d], dw = K_dw[d];
            const float d0 = (K_s0[d] == 0) ? xv : ((K_s0[d] == 1) ? x1 : x2);
            const float d1 = (K_s1[d] == 0) ? yv : ((K_s1[d] == 1) ? y1 : y2);
            const f32x2 d0v = {d0, d0}, d1v = {d1, d1};

            // layer 1: A1[m=pixel][k=o] = leaky(ahr + alr + d0*w0d0 + d1*w0d1)
            const f16x8 alv = *(const f16x8*)(alp + ((1 + dh) * 10 + (1 + dw)) * 40);
            f16x8 a1;
#pragma unroll
            for (int jp = 0; jp < 4; jp++) {
                f32x2 v = ah2[jp] + f32x2{(float)alv[2 * jp], (float)alv[2 * jp + 1]};
                v = __builtin_elementwise_fma(w0d0v[jp], d0v, v);   // == fmaf(d0, w0d0, v)
                v = __builtin_elementwise_fma(w0d1v[jp], d1v, v);
                v = __builtin_elementwise_max(v, v * 0.01f);        // leaky
                a1[2 * jp] = (_Float16)v[0];
                a1[2 * jp + 1] = (_Float16)v[1];
            }
            // layer 2 (K=32): one MFMA; leaky + stage D2 -> A3 layout (per-wave LDS)
            f32x4 acc2 = {0.f, 0.f, 0.f, 0.f};
            acc2 = __builtin_amdgcn_mfma_f32_16x16x32_f16(a1, w1B, acc2, 0, 0, 0);
#pragma unroll
            for (int r = 0; r < 4; r++) {
                const float v = fmaxf(acc2[r], 0.01f * acc2[r]);
                sd[(q * 4 + r) * 40 + m16] = (_Float16)v;
            }
            const f16x8 a3 = *(const f16x8*)&sd[m16 * 40 + q * 8];  // k>=16 reads zero pad
            // layer 3 (K=16 pad 32, N=8 pad 16): one MFMA
            f32x4 acc3 = {0.f, 0.f, 0.f, 0.f};
            acc3 = __builtin_amdgcn_mfma_f32_16x16x32_f16(a3, w2B, acc3, 0, 0, 0);

            // layer 4: w3.leaky(h3), summed over ch3 with a 3-step DPP butterfly.
            // sr[r] = logit of pixel t*16+q*4+r, valid in lanes m16 0..7.
            float sr[4];
#pragma unroll
            for (int r = 0; r < 4; r++)
                sr[r] = sum8(w3v * fmaxf(acc3[r], 0.01f * acc3[r]));
            float lv = sr[0];
            lv = (xm == 1) ? sr[1] : lv;
            lv = (xm == 2) ? sr[2] : lv;
            lv = (xm == 3) ? sr[3] : lv;
            const bool ok = ((unsigned)(h + 4 * dh) < (unsigned)HH) &&
                            ((unsigned)(wown + 4 * dw) < (unsigned)WW);
            l[d] = ok ? lv : -100.0f;
        }

        // in-lane softmax for this lane's own pixel (valid in lanes m16 0..7)
        float mx = l[0];
#pragma unroll
        for (int d = 1; d < 9; d++) mx = fmaxf(mx, l[d]);
        float s = 0.f;
#pragma unroll
        for (int d = 0; d < 9; d++) {
            l[d] = __expf(l[d] - mx);
            s += l[d];
        }
        const float inv = __builtin_amdgcn_rcpf(s);
        if (m16 < 4) {  // 16 writer lanes -> 64B coalesced store per direction
            float* op = out + (size_t)b * 9 * HW + (size_t)h * WW + (wp0 + t * 16 + q * 4 + m16);
#pragma unroll
            for (int d = 0; d < 9; d++) op[(size_t)d * HW] = l[d] * inv;
        }
    }
}

extern "C" void kernel_launch(void* const* d_in, const int* in_sizes, int n_in,
                              void* d_out, int out_size, void* d_ws, size_t ws_size,
                              hipStream_t stream) {
    const float* lr = (const float*)d_in[0];
    const float* hr = (const float*)d_in[1];
    // d_in[2], d_in[3] (lr_feature_r / hr_feature_r) are unused by the reference.
    const float* w0 = (const float*)d_in[4];
    const float* w1 = (const float*)d_in[5];
    const float* w2 = (const float*)d_in[6];
    const float* w3 = (const float*)d_in[7];
    float* out = (float*)d_out;

    const size_t alr_bytes = (size_t)BB * CH * CW * 32 * sizeof(float);  // 2 MB
    dim3 grid(WW / 32, HH / 16, BB);  // 512 blocks of 1024 thr (16 waves) -> 2 blocks/CU

    if (ws_size >= alr_bytes) {
        float* alr = (float*)d_ws;
        alr_prepass<<<(BB * CH * CW + 255) / 256, 256, 0, stream>>>(lr, w0, alr);
        ercm_mfma<true><<<grid, 1024, 0, stream>>>(hr, lr, alr, w0, w1, w2, w3, out);
    } else {
        ercm_mfma<false><<<grid, 1024, 0, stream>>>(hr, lr, nullptr, w0, w1, w2, w3, out);
    }
}

// Round 6
// 146.415 us; speedup vs baseline: 1.1039x; 1.1039x over previous
//
#include <hip/hip_runtime.h>
#include <math.h>

#define SC 4
#define BB 2
#define CC 32
#define HH 256
#define WW 512
#define CH (HH / SC)   // 64
#define CW (WW / SC)   // 128

using f16x8 = __attribute__((ext_vector_type(8))) _Float16;
using f32x4 = __attribute__((ext_vector_type(4))) float;
using f32x2 = __attribute__((ext_vector_type(2))) float;

// Direction metadata (output channel order: c, l, r, t, b, lt, rt, lb, rb)
//   s0: 0 -> xv (x[w%4]), 1 -> 4-(w%4) (D1), 2 -> (w%4)+1 (D2)
//   s1: 0 -> yv (x[h%4]), 1 -> 4-(h%4) (D3), 2 -> (h%4)+1 (D4)
constexpr int K_dh[9] = {0, 0, 0, -1, 1, -1, -1, 1, 1};
constexpr int K_dw[9] = {0, -1, 1, 0, 0, -1, 1, -1, 1};
constexpr int K_s0[9] = {0, 1, 2, 0, 0, 1, 2, 0, 0};
constexpr int K_s1[9] = {0, 0, 0, 1, 2, 0, 0, 1, 2};

__device__ __forceinline__ float swz_x16(float v) {
    // lane ^ 16 within each 32-lane half: BitMode offset = (16<<10)|0x1F
    return __int_as_float(__builtin_amdgcn_ds_swizzle(__float_as_int(v), 0x401F));
}

__device__ __forceinline__ int pack2h(float a, float b) {
    union { _Float16 h[2]; int i; } u;
    u.h[0] = (_Float16)a;   // RNE, same as old scalar casts
    u.h[1] = (_Float16)b;
    return u.i;
}

// Pre-pass: ALr[(b*CH+cy)*CW+cx][o] = sum_c w0[o*66+c] * lr[b][c][cy][cx]  (fp32)
__global__ __launch_bounds__(256) void alr_prepass(const float* __restrict__ lr,
                                                   const float* __restrict__ w0,
                                                   float* __restrict__ alr) {
    const int idx = blockIdx.x * 256 + threadIdx.x;
    if (idx >= BB * CH * CW) return;
    const int b = idx / (CH * CW);
    const int cell = idx - b * (CH * CW);
    const float* lp = lr + (size_t)b * CC * CH * CW + cell;
    float lv[32];
#pragma unroll
    for (int c = 0; c < 32; c++) lv[c] = lp[(size_t)c * (CH * CW)];
    float acc[32];
#pragma unroll
    for (int o = 0; o < 32; o++) {
        float a = 0.f;
#pragma unroll
        for (int c = 0; c < 32; c++) a = fmaf(lv[c], w0[o * 66 + c], a);
        acc[o] = a;
    }
    float4* op = (float4*)(alr + (size_t)idx * 32);
#pragma unroll
    for (int j = 0; j < 8; j++)
        op[j] = make_float4(acc[4 * j], acc[4 * j + 1], acc[4 * j + 2], acc[4 * j + 3]);
}

// MFMA main, R6: OPERAND-SWAP + DUAL-TILE ILP restructure.
// R5 post-mortem: occupancy counter pinned at ~32% across ALL residency
// levers (LDS 49.7->12.8KB, grid x2, 1024-thr blocks) -> stop chasing
// residency; the kernel is VALU-issue/latency-limited (VALUBusy ~50%,
// MfmaUtil 4%, HBM 6%). This round cuts VALU inst and doubles per-wave ILP:
//  (a) layer-2/3 MFMAs called with operands SWAPPED: mfma(w1B,a1),
//      mfma(w2B,a3). A/B fragments share the same lane->(idx,k) map, so the
//      inputs are bit-identical registers; outputs become D[ch][px].
//  (b) layer2->3 glue: D2[ch2][px] -> B3-frag needs a same-column q-exchange
//      only: 2 pack + 4 ds_bpermute (s_d2 LDS round-trip DELETED).
//  (c) layer-4: in-lane fma-chain over r (ch3=q*4+r) + swz(x16) + shfl(x32)
//      replaces the 24-inst DPP butterfly + selects.
//  (d) both 16-px tiles fused in one d-iteration: 2 independent dep chains
//      in every stall region; per-d dist vector dd computed once.
// Geometry: R4's (2048 blocks, 256 thr, 4 waves, 32 px/wave).
// __launch_bounds__(256,4) = 128-VGPR cap (R3 lesson: never force 8/EU).
template <bool USE_WS>
__global__ __launch_bounds__(256, 4) void ercm_mfma(const float* __restrict__ hr,
                                                    const float* __restrict__ lr,
                                                    const float* __restrict__ alr,
                                                    const float* __restrict__ w0,
                                                    const float* __restrict__ w1,
                                                    const float* __restrict__ w2,
                                                    const float* __restrict__ w3,
                                                    float* __restrict__ out) {
    __shared__ _Float16 s_alr[30 * 40];     // [cell][o], 3 x 10 halo of coarse cells
    __shared__ _Float16 s_ahr[4][32 * 40];  // per wave: [px 0..31][o] (both tiles)

    const int tid = threadIdx.x;
    const int lane = tid & 63;
    const int ty = tid >> 6;       // wave id = h-row within block
    const int m16 = lane & 15;
    const int q = lane >> 4;       // quad
    const int bx = blockIdx.x;     // 0..15
    const int by = blockIdx.y;     // 0..63
    const int b = blockIdx.z;      // 0..1
    const int h = by * 4 + ty;
    const int wp0 = bx * 32;
    const size_t HW = (size_t)HH * WW;

    // ---- stage ALr halo tile (3 x 10 coarse cells), f16 ----
    const int cy0 = by, cx0 = bx * 8;
    if (USE_WS) {
        for (int i = tid; i < 30 * 32; i += 256) {
            const int c = i & 31, cell = i >> 5;
            const int row = cell / 10, col = cell - row * 10;
            const int gcy = cy0 - 1 + row, gcx = cx0 - 1 + col;
            float v = 0.f;
            if ((unsigned)gcy < (unsigned)CH && (unsigned)gcx < (unsigned)CW)
                v = alr[(((size_t)b * CH + gcy) * CW + gcx) * 32 + c];
            s_alr[cell * 40 + c] = (_Float16)v;
        }
    } else {
        for (int i = tid; i < 30 * 32; i += 256) {
            const int o = i & 31, cell = i >> 5;
            const int row = cell / 10, col = cell - row * 10;
            const int gcy = cy0 - 1 + row, gcx = cx0 - 1 + col;
            float a = 0.f;
            if ((unsigned)gcy < (unsigned)CH && (unsigned)gcx < (unsigned)CW) {
                const float* lp = lr + (size_t)b * CC * CH * CW + (size_t)gcy * CW + gcx;
#pragma unroll
                for (int c = 0; c < 32; c++) a = fmaf(lp[(size_t)c * (CH * CW)], w0[o * 66 + c], a);
            }
            s_alr[cell * 40 + o] = (_Float16)a;
        }
    }

    // ---- load weight fragments (once). Same lane layout serves A or B. ----
    f16x8 w1B, w0hB0, w0hB1, w2B;
    {
        const float* p1 = w1 + m16 * 32 + q * 8;
        const float* p00 = w0 + m16 * 66 + 32 + q * 8;
        const float* p01 = w0 + (m16 + 16) * 66 + 32 + q * 8;
        const bool w2ok = (m16 < 8) && (q < 2);
#pragma unroll
        for (int j = 0; j < 8; j++) {
            w1B[j] = (_Float16)p1[j];
            w0hB0[j] = (_Float16)p00[j];
            w0hB1[j] = (_Float16)p01[j];
            w2B[j] = (_Float16)(w2ok ? w2[m16 * 16 + q * 8 + j] : 0.f);
        }
    }
    // layer-1 distance weights for this lane's channels o=q*8+j, as f32x2 pairs
    f32x2 w0d0v[4], w0d1v[4];
#pragma unroll
    for (int jp = 0; jp < 4; jp++) {
        w0d0v[jp] = f32x2{w0[(q * 8 + 2 * jp) * 66 + 64], w0[(q * 8 + 2 * jp + 1) * 66 + 64]};
        w0d1v[jp] = f32x2{w0[(q * 8 + 2 * jp) * 66 + 65], w0[(q * 8 + 2 * jp + 1) * 66 + 65]};
    }
    // layer-4 weights per D3 row ch3 = q*4+r (rows >=8 are exact zeros)
    float w3c[4];
#pragma unroll
    for (int r = 0; r < 4; r++) w3c[r] = (q < 2) ? w3[q * 4 + r] : 0.f;

    // per-lane distance operand values (pixel phase xm = w%4; ym wave-uniform)
    const int xm = m16 & 3;
    const float xv = (float)(xm < 2 ? xm - 2 : xm - 1);
    const float x1 = (float)(4 - xm), x2 = (float)(xm + 1);
    const int ym = h & 3;
    const float yv = (float)(ym < 2 ? ym - 2 : ym - 1);
    const float y1 = (float)(4 - ym), y2 = (float)(ym + 1);

    // bpermute byte-addresses for the q-exchange (target q pulls D2/D3 rows
    // from holder lanes m16+32q and m16+32q+16; q>=2 wraps -> garbage that is
    // multiplied by w2's zero K-rows, so it never contributes).
    const int A0 = ((m16 + 32 * q) & 63) << 2;
    const int A1 = ((m16 + 32 * q + 16) & 63) << 2;

    _Float16* sa = s_ahr[ty];

    __syncthreads();  // s_alr staged (everything else is per-wave)

    const float* hp = hr + (size_t)b * CC * HW + (size_t)h * WW + wp0;

    // ---- Phase A, both tiles: ahr = hr . w0hr via 4 MFMAs (D[px][ch]) ----
    f16x8 aT0, aT1;
#pragma unroll
    for (int j = 0; j < 8; j++) {
        aT0[j] = (_Float16)hp[(size_t)(q * 8 + j) * HW + m16];
        aT1[j] = (_Float16)hp[(size_t)(q * 8 + j) * HW + 16 + m16];
    }
    {
        f32x4 p00 = {0.f, 0.f, 0.f, 0.f}, p01 = {0.f, 0.f, 0.f, 0.f};
        f32x4 p10 = {0.f, 0.f, 0.f, 0.f}, p11 = {0.f, 0.f, 0.f, 0.f};
        p00 = __builtin_amdgcn_mfma_f32_16x16x32_f16(aT0, w0hB0, p00, 0, 0, 0);
        p01 = __builtin_amdgcn_mfma_f32_16x16x32_f16(aT0, w0hB1, p01, 0, 0, 0);
        p10 = __builtin_amdgcn_mfma_f32_16x16x32_f16(aT1, w0hB0, p10, 0, 0, 0);
        p11 = __builtin_amdgcn_mfma_f32_16x16x32_f16(aT1, w0hB1, p11, 0, 0, 0);
#pragma unroll
        for (int r = 0; r < 4; r++) {
            const int row = q * 4 + r;
            sa[row * 40 + m16] = (_Float16)p00[r];
            sa[row * 40 + 16 + m16] = (_Float16)p01[r];
            sa[(16 + row) * 40 + m16] = (_Float16)p10[r];
            sa[(16 + row) * 40 + 16 + m16] = (_Float16)p11[r];
        }
    }
    // hoist ahr to f32 registers ONCE per tile (reused by all 9 directions)
    const f16x8 ahv0 = *(const f16x8*)&sa[m16 * 40 + q * 8];
    const f16x8 ahv1 = *(const f16x8*)&sa[(16 + m16) * 40 + q * 8];
    f32x2 ah0[4], ah1[4];
#pragma unroll
    for (int jp = 0; jp < 4; jp++) {
        ah0[jp] = f32x2{(float)ahv0[2 * jp], (float)ahv0[2 * jp + 1]};
        ah1[jp] = f32x2{(float)ahv1[2 * jp], (float)ahv1[2 * jp + 1]};
    }

    // alr halo bases per tile; per-d cell adds a compile-time offset
    // ((1+dh)*10 + (1+dw)) * 40 halfs.
    const _Float16* alp0 = &s_alr[(m16 >> 2) * 40 + q * 8];
    const _Float16* alp1 = &s_alr[(4 + (m16 >> 2)) * 40 + q * 8];
    const int wown0 = wp0 + m16;        // this lane's pixel, tile 0 (q-uniform)
    const int wown1 = wp0 + 16 + m16;   // tile 1

    float l0[9], l1[9];
#pragma unroll
    for (int d = 0; d < 9; d++) {
        const int dh = K_dh[d], dw = K_dw[d];
        const float d0 = (K_s0[d] == 0) ? xv : ((K_s0[d] == 1) ? x1 : x2);
        const float d1 = (K_s1[d] == 0) ? yv : ((K_s1[d] == 1) ? y1 : y2);
        const f32x2 d0v = {d0, d0}, d1v = {d1, d1};
        const int off = ((1 + dh) * 10 + (1 + dw)) * 40;

        // shared per-d distance contribution (t-invariant)
        f32x2 dd[4];
#pragma unroll
        for (int jp = 0; jp < 4; jp++)
            dd[jp] = __builtin_elementwise_fma(w0d0v[jp], d0v, w0d1v[jp] * d1v);

        // layer 1 (both tiles): A1[k=ch1][n=px] = leaky(ahr + alr + dd)
        const f16x8 alv0 = *(const f16x8*)(alp0 + off);
        const f16x8 alv1 = *(const f16x8*)(alp1 + off);
        f16x8 a1_0, a1_1;
#pragma unroll
        for (int jp = 0; jp < 4; jp++) {
            f32x2 v0 = ah0[jp] + f32x2{(float)alv0[2 * jp], (float)alv0[2 * jp + 1]};
            f32x2 v1 = ah1[jp] + f32x2{(float)alv1[2 * jp], (float)alv1[2 * jp + 1]};
            v0 = v0 + dd[jp];
            v1 = v1 + dd[jp];
            v0 = __builtin_elementwise_max(v0, v0 * 0.01f);
            v1 = __builtin_elementwise_max(v1, v1 * 0.01f);
            a1_0[2 * jp] = (_Float16)v0[0];
            a1_0[2 * jp + 1] = (_Float16)v0[1];
            a1_1[2 * jp] = (_Float16)v1[0];
            a1_1[2 * jp + 1] = (_Float16)v1[1];
        }
        // layer 2 SWAPPED: D2[ch2][px] (lane: rows ch2=q*4+r, col px=m16)
        f32x4 c2_0 = {0.f, 0.f, 0.f, 0.f}, c2_1 = {0.f, 0.f, 0.f, 0.f};
        c2_0 = __builtin_amdgcn_mfma_f32_16x16x32_f16(w1B, a1_0, c2_0, 0, 0, 0);
        c2_1 = __builtin_amdgcn_mfma_f32_16x16x32_f16(w1B, a1_1, c2_1, 0, 0, 0);

        // layer2->3 glue: leaky, pack rows to f16 pairs, q-exchange via
        // 4 bpermutes -> B3-frag a3[k=ch2=q*8+j][n=px=m16]
        f16x8 a3_0, a3_1;
        {
            float e0 = fmaxf(c2_0[0], 0.01f * c2_0[0]), e1 = fmaxf(c2_0[1], 0.01f * c2_0[1]);
            float e2 = fmaxf(c2_0[2], 0.01f * c2_0[2]), e3 = fmaxf(c2_0[3], 0.01f * c2_0[3]);
            const int pk0 = pack2h(e0, e1), pk1 = pack2h(e2, e3);
            union { int i[4]; f16x8 v; } u;
            u.i[0] = __builtin_amdgcn_ds_bpermute(A0, pk0);
            u.i[1] = __builtin_amdgcn_ds_bpermute(A0, pk1);
            u.i[2] = __builtin_amdgcn_ds_bpermute(A1, pk0);
            u.i[3] = __builtin_amdgcn_ds_bpermute(A1, pk1);
            a3_0 = u.v;
        }
        {
            float e0 = fmaxf(c2_1[0], 0.01f * c2_1[0]), e1 = fmaxf(c2_1[1], 0.01f * c2_1[1]);
            float e2 = fmaxf(c2_1[2], 0.01f * c2_1[2]), e3 = fmaxf(c2_1[3], 0.01f * c2_1[3]);
            const int pk0 = pack2h(e0, e1), pk1 = pack2h(e2, e3);
            union { int i[4]; f16x8 v; } u;
            u.i[0] = __builtin_amdgcn_ds_bpermute(A0, pk0);
            u.i[1] = __builtin_amdgcn_ds_bpermute(A0, pk1);
            u.i[2] = __builtin_amdgcn_ds_bpermute(A1, pk0);
            u.i[3] = __builtin_amdgcn_ds_bpermute(A1, pk1);
            a3_1 = u.v;
        }
        // layer 3 SWAPPED: D3[ch3][px]; rows ch3>=8 exact 0 (w2 A-rows zero)
        f32x4 c3_0 = {0.f, 0.f, 0.f, 0.f}, c3_1 = {0.f, 0.f, 0.f, 0.f};
        c3_0 = __builtin_amdgcn_mfma_f32_16x16x32_f16(w2B, a3_0, c3_0, 0, 0, 0);
        c3_1 = __builtin_amdgcn_mfma_f32_16x16x32_f16(w2B, a3_1, c3_1, 0, 0, 0);

        // layer 4: in-lane fma over ch3=q*4+r, then sum the 4 q-partials
        // (lanes m16+16q) with swz(x16) + shfl(x32). Logit replicated in all
        // 64 lanes for px=m16.
        {
            float part = 0.f;
#pragma unroll
            for (int r = 0; r < 4; r++) {
                const float lv = fmaxf(c3_0[r], 0.01f * c3_0[r]);
                part = fmaf(w3c[r], lv, part);
            }
            float s2 = part + swz_x16(part);
            const float lg = s2 + __shfl_xor(s2, 32, 64);
            const bool ok = ((unsigned)(h + 4 * dh) < (unsigned)HH) &&
                            ((unsigned)(wown0 + 4 * dw) < (unsigned)WW);
            l0[d] = ok ? lg : -100.0f;
        }
        {
            float part = 0.f;
#pragma unroll
            for (int r = 0; r < 4; r++) {
                const float lv = fmaxf(c3_1[r], 0.01f * c3_1[r]);
                part = fmaf(w3c[r], lv, part);
            }
            float s2 = part + swz_x16(part);
            const float lg = s2 + __shfl_xor(s2, 32, 64);
            const bool ok = ((unsigned)(h + 4 * dh) < (unsigned)HH) &&
                            ((unsigned)(wown1 + 4 * dw) < (unsigned)WW);
            l1[d] = ok ? lg : -100.0f;
        }
    }

    // softmax per tile (replicated across q; lane owns px=m16); writers q==0
    {
        float mx = l0[0];
#pragma unroll
        for (int d = 1; d < 9; d++) mx = fmaxf(mx, l0[d]);
        float s = 0.f;
#pragma unroll
        for (int d = 0; d < 9; d++) {
            l0[d] = __expf(l0[d] - mx);
            s += l0[d];
        }
        const float inv = __builtin_amdgcn_rcpf(s);
        if (lane < 16) {
            float* op = out + (size_t)b * 9 * HW + (size_t)h * WW + wown0;
#pragma unroll
            for (int d = 0; d < 9; d++) op[(size_t)d * HW] = l0[d] * inv;
        }
    }
    {
        float mx = l1[0];
#pragma unroll
        for (int d = 1; d < 9; d++) mx = fmaxf(mx, l1[d]);
        float s = 0.f;
#pragma unroll
        for (int d = 0; d < 9; d++) {
            l1[d] = __expf(l1[d] - mx);
            s += l1[d];
        }
        const float inv = __builtin_amdgcn_rcpf(s);
        if (lane < 16) {
            float* op = out + (size_t)b * 9 * HW + (size_t)h * WW + wown1;
#pragma unroll
            for (int d = 0; d < 9; d++) op[(size_t)d * HW] = l1[d] * inv;
        }
    }
}

extern "C" void kernel_launch(void* const* d_in, const int* in_sizes, int n_in,
                              void* d_out, int out_size, void* d_ws, size_t ws_size,
                              hipStream_t stream) {
    const float* lr = (const float*)d_in[0];
    const float* hr = (const float*)d_in[1];
    // d_in[2], d_in[3] (lr_feature_r / hr_feature_r) are unused by the reference.
    const float* w0 = (const float*)d_in[4];
    const float* w1 = (const float*)d_in[5];
    const float* w2 = (const float*)d_in[6];
    const float* w3 = (const float*)d_in[7];
    float* out = (float*)d_out;

    const size_t alr_bytes = (size_t)BB * CH * CW * 32 * sizeof(float);  // 2 MB
    dim3 grid(WW / 32, HH / 4, BB);  // 2048 blocks of 256 thr (4 waves)

    if (ws_size >= alr_bytes) {
        float* alr = (float*)d_ws;
        alr_prepass<<<(BB * CH * CW + 255) / 256, 256, 0, stream>>>(lr, w0, alr);
        ercm_mfma<true><<<grid, 256, 0, stream>>>(hr, lr, alr, w0, w1, w2, w3, out);
    } else {
        ercm_mfma<false><<<grid, 256, 0, stream>>>(hr, lr, nullptr, w0, w1, w2, w3, out);
    }
}